// Round 5
// baseline (4010.518 us; speedup 1.0000x reference)
//
#include <hip/hip_runtime.h>

#define B_   8
#define N1_  8192
#define N2_  1024
#define K_   32
#define F1_  64
#define CIN_ 67
#define M1_  64
#define M2_  64
#define M3_  128
#define HSTR 40          // LDS activation row stride (floats)
#define SSTR 36          // KNN d2 per-thread chunk stride (floats)
#define FLTMAX 3.402823466e+38f

// ---------------- FPS: one block per batch, sequential greedy farthest-point sampling ----------------
__global__ __launch_bounds__(256, 1) void fps_kernel(const float* __restrict__ xyz,
                                                     float* __restrict__ out_xyz)
{
  __shared__ int selarr[N2_];
  __shared__ float redv[4];
  __shared__ int   redi[4];
  __shared__ float pbc[3];

  const int t = threadIdx.x;
  const int b = blockIdx.x;
  const float* gxyz = xyz + (size_t)b * (N1_ * 3);

  // stage 32 points per thread into registers (f32 exact)
  float x[32], y[32], z[32], md[32];
  {
    const float4* gs = (const float4*)gxyz;
#pragma unroll
    for (int w = 0; w < 24; ++w) {
      const float4 v = gs[t * 24 + w];
#pragma unroll
      for (int c = 0; c < 4; ++c) {
        const int p = w * 4 + c;               // flat float index 0..95
        const float val = (c == 0) ? v.x : (c == 1) ? v.y : (c == 2) ? v.z : v.w;
        const int j = p / 3, cc = p % 3;
        if (cc == 0) x[j] = val; else if (cc == 1) y[j] = val; else z[j] = val;
      }
    }
  }
#pragma unroll
  for (int j = 0; j < 32; ++j) md[j] = FLTMAX;  // matches jnp.finfo(float32).max init

  if (t == 0) { selarr[0] = 0; pbc[0] = x[0]; pbc[1] = y[0]; pbc[2] = z[0]; }
  __syncthreads();

  const int n0 = t * 32;
  for (int i = 1; i < N2_; ++i) {
    const float px = pbc[0], py = pbc[1], pz = pbc[2];
    // fma-free, reference-ordered distance: ((dx^2+dy^2)+dz^2), all f32
#pragma unroll
    for (int j = 0; j < 32; ++j) {
      float dx = __fsub_rn(x[j], px);
      float dy = __fsub_rn(y[j], py);
      float dz = __fsub_rn(z[j], pz);
      float d  = __fadd_rn(__fadd_rn(__fmul_rn(dx,dx), __fmul_rn(dy,dy)), __fmul_rn(dz,dz));
      md[j] = fminf(md[j], d);
    }
    // tree argmax (first-index tie-break; left operand always lower point index)
    float tv[16]; int ti[16];
#pragma unroll
    for (int s = 0; s < 16; ++s) {
      bool c = md[2*s+1] > md[2*s];
      tv[s] = c ? md[2*s+1] : md[2*s];
      ti[s] = c ? (n0 + 2*s + 1) : (n0 + 2*s);
    }
#pragma unroll
    for (int w = 8; w >= 1; w >>= 1) {
#pragma unroll
      for (int s = 0; s < w; ++s) {
        bool c = tv[s + w] > tv[s];
        tv[s] = c ? tv[s+w] : tv[s];
        ti[s] = c ? ti[s+w] : ti[s];
      }
    }
    float bv = tv[0]; int bi = ti[0];
#pragma unroll
    for (int off = 32; off >= 1; off >>= 1) {
      float ov = __shfl_down(bv, off, 64);
      int   oi = __shfl_down(bi, off, 64);
      if (ov > bv || (ov == bv && oi < bi)) { bv = ov; bi = oi; }
    }
    if ((t & 63) == 0) { redv[t >> 6] = bv; redi[t >> 6] = bi; }
    __syncthreads();
    if (t == 0) {
      float wv = redv[0]; int wix = redi[0];
#pragma unroll
      for (int u = 1; u < 4; ++u) {
        if (redv[u] > wv || (redv[u] == wv && redi[u] < wix)) { wv = redv[u]; wix = redi[u]; }
      }
      wix &= (N1_ - 1);
      selarr[i] = wix;
      pbc[0] = gxyz[3*wix+0];   // exact f32 winner coords (L2-hit)
      pbc[1] = gxyz[3*wix+1];
      pbc[2] = gxyz[3*wix+2];
    }
    __syncthreads();
  }
  // exact f32 selected_xyz (bitwise gather copy)
  for (int q = t; q < N2_; q += 256) {
    const int n = selarr[q];
    const int o = (b * N2_ + q) * 3;
    out_xyz[o+0] = gxyz[3*n+0];
    out_xyz[o+1] = gxyz[3*n+1];
    out_xyz[o+2] = gxyz[3*n+2];
  }
}

// ---------------- Fused KNN + MLP + maxpool: one block per query ----------------
// LDS union: phase 1 d2s (36864 B); phase 2 [wreg 33536 | buf0 10720 | buf1 10240] = 54496 B.
#define SMEM_BYTES 54496
#define OFF_B0 33536
#define OFF_B1 (OFF_B0 + CIN_*HSTR*4)

__global__ __launch_bounds__(256) void knn_mlp_kernel(
    const float* __restrict__ xyz, const float* __restrict__ feat,
    const float* __restrict__ w0g, const float* __restrict__ b0g,
    const float* __restrict__ w1g, const float* __restrict__ b1g,
    const float* __restrict__ w2g, const float* __restrict__ b2g,
    const float* __restrict__ sel_xyz, float* __restrict__ out_feat)
{
  __shared__ __align__(16) char smem[SMEM_BYTES];
  __shared__ float b0s[M1_], b1s[M2_], b2s[M3_];
  __shared__ float redv[4];
  __shared__ int   redi[4];
  __shared__ int   kn_idx[K_];
  __shared__ float kn_d[K_];

  float* d2s  = (float*)smem;
  float* wreg = (float*)smem;                  // phase-2 weight region
  float* buf0 = (float*)(smem + OFF_B0);
  float* buf1 = (float*)(smem + OFF_B1);

  const int t  = threadIdx.x;
  const int bq = blockIdx.x;
  const int b  = bq >> 10;
  const float* gxyz = xyz + (size_t)b * (N1_ * 3);

  // exact f32 query coords (written by fps_kernel into d_out's xyz section)
  const float qx = sel_xyz[bq*3+0], qy = sel_xyz[bq*3+1], qz = sel_xyz[bq*3+2];
  const float q2 = __fadd_rn(__fadd_rn(__fmul_rn(qx,qx), __fmul_rn(qy,qy)), __fmul_rn(qz,qz));

  // d2 = (q2 + p2) - 2*qp, fma-free, exactly the reference op order
  {
    float px[32], py[32], pz[32];
    const float4* gs = (const float4*)gxyz;
#pragma unroll
    for (int w = 0; w < 24; ++w) {
      const float4 v = gs[t * 24 + w];
#pragma unroll
      for (int c = 0; c < 4; ++c) {
        const int p = w * 4 + c;
        const float val = (c == 0) ? v.x : (c == 1) ? v.y : (c == 2) ? v.z : v.w;
        const int j = p / 3, cc = p % 3;
        if (cc == 0) px[j] = val; else if (cc == 1) py[j] = val; else pz[j] = val;
      }
    }
#pragma unroll
    for (int g = 0; g < 8; ++g) {
      float vv[4];
#pragma unroll
      for (int c = 0; c < 4; ++c) {
        const int j = 4*g + c;
        const float p2 = __fadd_rn(__fadd_rn(__fmul_rn(px[j],px[j]), __fmul_rn(py[j],py[j])), __fmul_rn(pz[j],pz[j]));
        const float qp = __fadd_rn(__fadd_rn(__fmul_rn(qx,px[j]), __fmul_rn(qy,py[j])), __fmul_rn(qz,pz[j]));
        vv[c] = __fsub_rn(__fadd_rn(q2, p2), __fmul_rn(2.0f, qp));
      }
      float4 dv; dv.x = vv[0]; dv.y = vv[1]; dv.z = vv[2]; dv.w = vv[3];
      *(float4*)&d2s[t * SSTR + 4*g] = dv;
    }
  }
  __syncthreads();

  // iterative top-32 by block argmin (ties -> lower index, matches stable top_k)
  for (int kk = 0; kk < K_; ++kk) {
    float mv = FLTMAX; int mi = 0;
#pragma unroll
    for (int g = 0; g < 8; ++g) {
      const float4 v = *(const float4*)&d2s[t * SSTR + 4*g];
      const int nb = t*32 + 4*g;
      if (v.x < mv) { mv = v.x; mi = nb;   }
      if (v.y < mv) { mv = v.y; mi = nb+1; }
      if (v.z < mv) { mv = v.z; mi = nb+2; }
      if (v.w < mv) { mv = v.w; mi = nb+3; }
    }
#pragma unroll
    for (int off = 32; off >= 1; off >>= 1) {
      float ov = __shfl_down(mv, off, 64);
      int   oi = __shfl_down(mi, off, 64);
      if (ov < mv || (ov == mv && oi < mi)) { mv = ov; mi = oi; }
    }
    if ((t & 63) == 0) { redv[t >> 6] = mv; redi[t >> 6] = mi; }
    __syncthreads();
    if (t == 0) {
      float wv = redv[0]; int wi = redi[0];
#pragma unroll
      for (int u = 1; u < 4; ++u) {
        if (redv[u] < wv || (redv[u] == wv && redi[u] < wi)) { wv = redv[u]; wi = redi[u]; }
      }
      const int wc = wi & (N1_ - 1);
      kn_idx[kk] = wc; kn_d[kk] = wv;
      d2s[(wc >> 5) * SSTR + (wc & 31)] = FLTMAX;
    }
    __syncthreads();
  }

  // -------- phase 2: stage W0+W1 (overwrites d2s), gather h0, MLP, maxpool --------
  for (int i = t; i < (CIN_*M1_)/4; i += 256) ((float4*)wreg)[i] = ((const float4*)w0g)[i];
  {
    float4* w1dst = (float4*)(wreg + CIN_*M1_);
    for (int i = t; i < (M1_*M2_)/4; i += 256) w1dst[i] = ((const float4*)w1g)[i];
  }
  if (t < M1_) { b0s[t] = b0g[t]; b1s[t] = b1g[t]; }
  if (t < M3_) { b2s[t] = b2g[t]; }

  // gather h0 (c-major): rows 0..2 = relative xyz, rows 3..66 = features
  {
    const int k = t >> 3, fg = t & 7;
    int nk = kn_idx[k];
    if (kn_d[k] > 0.04f) nk = kn_idx[0];   // ball-query radius clamp (see note: equiv. to f64 compare)
    nk &= (N1_ - 1);
    const float* frow = feat + ((size_t)(b * N1_ + nk)) * F1_ + fg * 8;
    const float4 f0 = *(const float4*)frow;
    const float4 f1 = *(const float4*)(frow + 4);
    const int fb = 3 + fg * 8;
    buf0[(fb+0)*HSTR + k] = f0.x;
    buf0[(fb+1)*HSTR + k] = f0.y;
    buf0[(fb+2)*HSTR + k] = f0.z;
    buf0[(fb+3)*HSTR + k] = f0.w;
    buf0[(fb+4)*HSTR + k] = f1.x;
    buf0[(fb+5)*HSTR + k] = f1.y;
    buf0[(fb+6)*HSTR + k] = f1.z;
    buf0[(fb+7)*HSTR + k] = f1.w;
    if (fg < 3) {
      const float pc = gxyz[(size_t)nk * 3 + fg];
      const float qc = (fg == 0) ? qx : (fg == 1) ? qy : qz;
      buf0[fg * HSTR + k] = __fsub_rn(pc, qc);
    }
  }
  __syncthreads();

#define LEAKY_STORE(acc, mi_, bias, hout) { \
    const float bb = bias[mg*4 + (mi_)]; \
    float4 v; \
    v.x = acc.x + bb; v.x = fmaxf(v.x, 0.2f*v.x); \
    v.y = acc.y + bb; v.y = fmaxf(v.y, 0.2f*v.y); \
    v.z = acc.z + bb; v.z = fmaxf(v.z, 0.2f*v.z); \
    v.w = acc.w + bb; v.w = fmaxf(v.w, 0.2f*v.w); \
    *(float4*)&hout[(mg*4 + (mi_)) * HSTR + kq * 4] = v; }

  // layer 1: 67 -> 64 (threads 0..127, 4m x 4k register tile)
  if (t < 128) {
    const int kq = t & 7, mg = t >> 3;
    float4 a0 = {0,0,0,0}, a1 = {0,0,0,0}, a2 = {0,0,0,0}, a3 = {0,0,0,0};
    const float* w0s = wreg;
    for (int c = 0; c < CIN_; ++c) {
      const float4 wp = *(const float4*)&w0s[c * M1_ + mg * 4];
      const float4 h  = *(const float4*)&buf0[c * HSTR + kq * 4];
      a0.x += h.x*wp.x; a0.y += h.y*wp.x; a0.z += h.z*wp.x; a0.w += h.w*wp.x;
      a1.x += h.x*wp.y; a1.y += h.y*wp.y; a1.z += h.z*wp.y; a1.w += h.w*wp.y;
      a2.x += h.x*wp.z; a2.y += h.y*wp.z; a2.z += h.z*wp.z; a2.w += h.w*wp.z;
      a3.x += h.x*wp.w; a3.y += h.y*wp.w; a3.z += h.z*wp.w; a3.w += h.w*wp.w;
    }
    LEAKY_STORE(a0, 0, b0s, buf1) LEAKY_STORE(a1, 1, b0s, buf1)
    LEAKY_STORE(a2, 2, b0s, buf1) LEAKY_STORE(a3, 3, b0s, buf1)
  }
  __syncthreads();

  // layer 2: 64 -> 64
  if (t < 128) {
    const int kq = t & 7, mg = t >> 3;
    float4 a0 = {0,0,0,0}, a1 = {0,0,0,0}, a2 = {0,0,0,0}, a3 = {0,0,0,0};
    const float* w1s = wreg + CIN_*M1_;
    for (int c = 0; c < M1_; ++c) {
      const float4 wp = *(const float4*)&w1s[c * M2_ + mg * 4];
      const float4 h  = *(const float4*)&buf1[c * HSTR + kq * 4];
      a0.x += h.x*wp.x; a0.y += h.y*wp.x; a0.z += h.z*wp.x; a0.w += h.w*wp.x;
      a1.x += h.x*wp.y; a1.y += h.y*wp.y; a1.z += h.z*wp.y; a1.w += h.w*wp.y;
      a2.x += h.x*wp.z; a2.y += h.y*wp.z; a2.z += h.z*wp.z; a2.w += h.w*wp.z;
      a3.x += h.x*wp.w; a3.y += h.y*wp.w; a3.z += h.z*wp.w; a3.w += h.w*wp.w;
    }
    LEAKY_STORE(a0, 0, b1s, buf0) LEAKY_STORE(a1, 1, b1s, buf0)
    LEAKY_STORE(a2, 2, b1s, buf0) LEAKY_STORE(a3, 3, b1s, buf0)
  }
#undef LEAKY_STORE
  __syncthreads();

  // stage W2 (32 KB) over W0/W1
  for (int i = t; i < (M2_*M3_)/4; i += 256) ((float4*)wreg)[i] = ((const float4*)w2g)[i];
  __syncthreads();

  // layer 3: 64 -> 128, + maxpool over k
  {
    const int kq = t & 7, mg = t >> 3;   // mg in 0..31
    float4 a0 = {0,0,0,0}, a1 = {0,0,0,0}, a2 = {0,0,0,0}, a3 = {0,0,0,0};
    for (int c = 0; c < M2_; ++c) {
      const float4 wp = *(const float4*)&wreg[c * M3_ + mg * 4];
      const float4 h  = *(const float4*)&buf0[c * HSTR + kq * 4];
      a0.x += h.x*wp.x; a0.y += h.y*wp.x; a0.z += h.z*wp.x; a0.w += h.w*wp.x;
      a1.x += h.x*wp.y; a1.y += h.y*wp.y; a1.z += h.z*wp.y; a1.w += h.w*wp.y;
      a2.x += h.x*wp.z; a2.y += h.y*wp.z; a2.z += h.z*wp.z; a2.w += h.w*wp.z;
      a3.x += h.x*wp.w; a3.y += h.y*wp.w; a3.z += h.z*wp.w; a3.w += h.w*wp.w;
    }
    float vm[4];
#define BIAS_LEAKY_HMAX(acc, mi_) { \
      const float bb = b2s[mg*4 + (mi_)]; \
      float vx = acc.x + bb; vx = fmaxf(vx, 0.2f*vx); \
      float vy = acc.y + bb; vy = fmaxf(vy, 0.2f*vy); \
      float vz = acc.z + bb; vz = fmaxf(vz, 0.2f*vz); \
      float vw = acc.w + bb; vw = fmaxf(vw, 0.2f*vw); \
      vm[mi_] = fmaxf(fmaxf(vx, vy), fmaxf(vz, vw)); }
    BIAS_LEAKY_HMAX(a0, 0) BIAS_LEAKY_HMAX(a1, 1) BIAS_LEAKY_HMAX(a2, 2) BIAS_LEAKY_HMAX(a3, 3)
#undef BIAS_LEAKY_HMAX
#pragma unroll
    for (int m = 1; m <= 4; m <<= 1) {
      vm[0] = fmaxf(vm[0], __shfl_xor(vm[0], m, 64));
      vm[1] = fmaxf(vm[1], __shfl_xor(vm[1], m, 64));
      vm[2] = fmaxf(vm[2], __shfl_xor(vm[2], m, 64));
      vm[3] = fmaxf(vm[3], __shfl_xor(vm[3], m, 64));
    }
    if (kq == 0) {
      float4 o; o.x = vm[0]; o.y = vm[1]; o.z = vm[2]; o.w = vm[3];
      *(float4*)&out_feat[(size_t)bq * M3_ + mg * 4] = o;
    }
  }
}

extern "C" void kernel_launch(void* const* d_in, const int* in_sizes, int n_in,
                              void* d_out, int out_size, void* d_ws, size_t ws_size,
                              hipStream_t stream) {
  const float* xyz  = (const float*)d_in[0];
  const float* feat = (const float*)d_in[1];
  const float* w0   = (const float*)d_in[2];
  const float* b0   = (const float*)d_in[3];
  const float* w1   = (const float*)d_in[4];
  const float* b1   = (const float*)d_in[5];
  const float* w2   = (const float*)d_in[6];
  const float* b2   = (const float*)d_in[7];

  float* out_xyz  = (float*)d_out;                  // (8,1024,3) f32
  float* out_feat = out_xyz + B_ * N2_ * 3;         // (8,1024,128) f32

  fps_kernel<<<B_, 256, 0, stream>>>(xyz, out_xyz);
  knn_mlp_kernel<<<B_ * N2_, 256, 0, stream>>>(xyz, feat, w0, b0, w1, b1, w2, b2,
                                               out_xyz, out_feat);
}

// Round 6
// 2452.208 us; speedup vs baseline: 1.6355x; 1.6355x over previous
//
#include <hip/hip_runtime.h>

#define B_   8
#define N1_  8192
#define N2_  1024
#define K_   32
#define F1_  64
#define CIN_ 67
#define M1_  64
#define M2_  64
#define M3_  128
#define HSTR 40          // LDS activation row stride (floats)
#define SSTR 36          // KNN d2 per-thread chunk stride (floats)
#define FLTMAX 3.402823466e+38f

#define FTPB 512         // FPS threads per block
#define FNW  (FTPB/64)   // FPS waves per block
#define PPT  (N1_/FTPB)  // points per thread = 16

// ---------------- FPS: one block per batch, single barrier per iteration ----------------
__global__ __launch_bounds__(FTPB, 1) void fps_kernel(const float* __restrict__ xyz,
                                                      float* __restrict__ out_xyz)
{
  __shared__ float wval[2][FNW], wxs[2][FNW], wys[2][FNW], wzs[2][FNW];
  __shared__ int   widx[2][FNW];
  __shared__ int   selarr[N2_];

  const int t = threadIdx.x;
  const int b = blockIdx.x;
  const float* gxyz = xyz + (size_t)b * (N1_ * 3);

  // stage PPT points per thread into registers (f32 exact)
  float x[PPT], y[PPT], z[PPT], md[PPT];
  {
    const float4* gs = (const float4*)gxyz;
#pragma unroll
    for (int w = 0; w < 12; ++w) {
      const float4 v = gs[t * 12 + w];
#pragma unroll
      for (int c = 0; c < 4; ++c) {
        const int p = w * 4 + c;               // flat float index 0..47
        const float val = (c == 0) ? v.x : (c == 1) ? v.y : (c == 2) ? v.z : v.w;
        const int j = p / 3, cc = p % 3;
        if (cc == 0) x[j] = val; else if (cc == 1) y[j] = val; else z[j] = val;
      }
    }
  }
#pragma unroll
  for (int j = 0; j < PPT; ++j) md[j] = FLTMAX;  // matches jnp.finfo(float32).max init

  // seed slots (parity 1) so iteration 1 selects point 0
  if ((t & 63) == 0) wval[1][t >> 6] = (t >> 6 == 0) ? 1.0f : -1.0f;
  if (t == 0) { wxs[1][0] = x[0]; wys[1][0] = y[0]; wzs[1][0] = z[0]; widx[1][0] = 0; }
  __syncthreads();

  const int n0 = t * PPT;
  const int lane = t & 63, wv_ = t >> 6;

  for (int i = 1; i < N2_; ++i) {
    const int p = i & 1;
    // (A) redundant winner scan over wave slots (strict > keeps lowest wave = lowest idx)
    float bvs = wval[p][0]; int win = 0;
#pragma unroll
    for (int u = 1; u < FNW; ++u) { const float v = wval[p][u]; if (v > bvs) { bvs = v; win = u; } }
    const float px = wxs[p][win], py = wys[p][win], pz = wzs[p][win];
    if (t == 0) selarr[i - 1] = widx[p][win];

    // (B) fused distance update + first-max argmax with inline coord tracking
    float bestv, bx, by, bz; int besti;
#pragma unroll
    for (int j = 0; j < PPT; ++j) {
      const float dx = __fsub_rn(x[j], px);
      const float dy = __fsub_rn(y[j], py);
      const float dz = __fsub_rn(z[j], pz);
      const float d  = __fadd_rn(__fadd_rn(__fmul_rn(dx,dx), __fmul_rn(dy,dy)), __fmul_rn(dz,dz));
      md[j] = fminf(md[j], d);
      if (j == 0) { bestv = md[0]; bx = x[0]; by = y[0]; bz = z[0]; besti = n0; }
      else {
        const bool c = md[j] > bestv;
        bestv = c ? md[j] : bestv;
        bx = c ? x[j] : bx; by = c ? y[j] : by; bz = c ? z[j] : bz;
        besti = c ? (n0 + j) : besti;
      }
    }
    // (C) value-only wave butterfly; ballot picks winner lane (lowest lane = lowest idx)
    float wmax = bestv;
#pragma unroll
    for (int m = 1; m <= 32; m <<= 1) wmax = fmaxf(wmax, __shfl_xor(wmax, m, 64));
    const unsigned long long bm = __ballot(bestv == wmax);
    const int fl = __ffsll(bm) - 1;
    if (lane == fl) {
      const int q = 1 - p;
      wval[q][wv_] = bestv; wxs[q][wv_] = bx; wys[q][wv_] = by; wzs[q][wv_] = bz;
      widx[q][wv_] = besti;
    }
    __syncthreads();
  }
  // final winner (written with parity (N2_)&1 == 0)
  {
    float bvs = wval[0][0]; int win = 0;
#pragma unroll
    for (int u = 1; u < FNW; ++u) { const float v = wval[0][u]; if (v > bvs) { bvs = v; win = u; } }
    if (t == 0) selarr[N2_ - 1] = widx[0][win];
  }
  __syncthreads();

  // exact f32 selected_xyz (bitwise gather copy)
  for (int q = t; q < N2_; q += FTPB) {
    const int n = selarr[q];
    const int o = (b * N2_ + q) * 3;
    out_xyz[o+0] = gxyz[3*n+0];
    out_xyz[o+1] = gxyz[3*n+1];
    out_xyz[o+2] = gxyz[3*n+2];
  }
}

// ---------------- Fused KNN + MLP + maxpool: one block per query ----------------
// LDS union: phase 1 d2s (36864 B); phase 2 [wreg 33536 | buf0 10720 | buf1 10240] = 54496 B.
#define SMEM_BYTES 54496
#define OFF_B0 33536
#define OFF_B1 (OFF_B0 + CIN_*HSTR*4)

__global__ __launch_bounds__(256) void knn_mlp_kernel(
    const float* __restrict__ xyz, const float* __restrict__ feat,
    const float* __restrict__ w0g, const float* __restrict__ b0g,
    const float* __restrict__ w1g, const float* __restrict__ b1g,
    const float* __restrict__ w2g, const float* __restrict__ b2g,
    const float* __restrict__ sel_xyz, float* __restrict__ out_feat)
{
  __shared__ __align__(16) char smem[SMEM_BYTES];
  __shared__ float b0s[M1_], b1s[M2_], b2s[M3_];
  __shared__ float sval[2][4];
  __shared__ int   sidx[2][4];

  float* d2s  = (float*)smem;
  float* wreg = (float*)smem;                  // phase-2 weight region
  float* buf0 = (float*)(smem + OFF_B0);
  float* buf1 = (float*)(smem + OFF_B1);

  const int t  = threadIdx.x;
  const int bq = blockIdx.x;
  const int b  = bq >> 10;
  const float* gxyz = xyz + (size_t)b * (N1_ * 3);

  // exact f32 query coords (written by fps_kernel into d_out's xyz section)
  const float qx = sel_xyz[bq*3+0], qy = sel_xyz[bq*3+1], qz = sel_xyz[bq*3+2];
  const float q2 = __fadd_rn(__fadd_rn(__fmul_rn(qx,qx), __fmul_rn(qy,qy)), __fmul_rn(qz,qz));

  // d2 = (q2 + p2) - 2*qp, fma-free, exactly the reference op order
  {
    float px[32], py[32], pz[32];
    const float4* gs = (const float4*)gxyz;
#pragma unroll
    for (int w = 0; w < 24; ++w) {
      const float4 v = gs[t * 24 + w];
#pragma unroll
      for (int c = 0; c < 4; ++c) {
        const int p = w * 4 + c;
        const float val = (c == 0) ? v.x : (c == 1) ? v.y : (c == 2) ? v.z : v.w;
        const int j = p / 3, cc = p % 3;
        if (cc == 0) px[j] = val; else if (cc == 1) py[j] = val; else pz[j] = val;
      }
    }
#pragma unroll
    for (int g = 0; g < 8; ++g) {
      float vv[4];
#pragma unroll
      for (int c = 0; c < 4; ++c) {
        const int j = 4*g + c;
        const float p2 = __fadd_rn(__fadd_rn(__fmul_rn(px[j],px[j]), __fmul_rn(py[j],py[j])), __fmul_rn(pz[j],pz[j]));
        const float qp = __fadd_rn(__fadd_rn(__fmul_rn(qx,px[j]), __fmul_rn(qy,py[j])), __fmul_rn(qz,pz[j]));
        vv[c] = __fsub_rn(__fadd_rn(q2, p2), __fmul_rn(2.0f, qp));
      }
      float4 dv; dv.x = vv[0]; dv.y = vv[1]; dv.z = vv[2]; dv.w = vv[3];
      *(float4*)&d2s[t * SSTR + 4*g] = dv;
    }
  }
  __syncthreads();

  // iterative top-32: single barrier per round, redundant winner extraction, owner-poke exclusion
  int   myk_idx = 0;      // winner idx for k == t>>3 (captured in-register)
  float myk_d   = 0.0f;
  int   k0_idx  = 0;      // winner idx of round 0 (radius fallback)
  for (int kk = 0; kk < K_; ++kk) {
    if (kk > 0) {
      const int p = (kk - 1) & 1;
      float wv = sval[p][0]; int wi = sidx[p][0];
#pragma unroll
      for (int u = 1; u < 4; ++u) {
        const float v = sval[p][u]; const int ii = sidx[p][u];
        if (v < wv || (v == wv && ii < wi)) { wv = v; wi = ii; }
      }
      const int wc = wi & (N1_ - 1);
      if (t == (wc >> 5)) d2s[(wc >> 5) * SSTR + (wc & 31)] = FLTMAX;  // only owner rescans this cell
      if ((t >> 3) == (kk - 1)) { myk_idx = wc; myk_d = wv; }
      if (kk == 1) k0_idx = wc;
    }
    // per-thread scan of own 32 d2 values
    float mv = FLTMAX; int mi = 0;
#pragma unroll
    for (int g = 0; g < 8; ++g) {
      const float4 v = *(const float4*)&d2s[t * SSTR + 4*g];
      const int nb = t*32 + 4*g;
      if (v.x < mv) { mv = v.x; mi = nb;   }
      if (v.y < mv) { mv = v.y; mi = nb+1; }
      if (v.z < mv) { mv = v.z; mi = nb+2; }
      if (v.w < mv) { mv = v.w; mi = nb+3; }
    }
    // wave butterfly (all lanes get wave min with lowest-idx ties)
#pragma unroll
    for (int off = 1; off <= 32; off <<= 1) {
      const float ov = __shfl_xor(mv, off, 64);
      const int   oi = __shfl_xor(mi, off, 64);
      if (ov < mv || (ov == mv && oi < mi)) { mv = ov; mi = oi; }
    }
    if ((t & 63) == 0) { sval[kk & 1][t >> 6] = mv; sidx[kk & 1][t >> 6] = mi; }
    __syncthreads();
  }
  // extract winner of round 31 (parity 1)
  {
    float wv = sval[1][0]; int wi = sidx[1][0];
#pragma unroll
    for (int u = 1; u < 4; ++u) {
      const float v = sval[1][u]; const int ii = sidx[1][u];
      if (v < wv || (v == wv && ii < wi)) { wv = v; wi = ii; }
    }
    const int wc = wi & (N1_ - 1);
    if ((t >> 3) == (K_ - 1)) { myk_idx = wc; myk_d = wv; }
  }

  // -------- phase 2: stage W0+W1 (overwrites d2s), gather h0, MLP, maxpool --------
  for (int i = t; i < (CIN_*M1_)/4; i += 256) ((float4*)wreg)[i] = ((const float4*)w0g)[i];
  {
    float4* w1dst = (float4*)(wreg + CIN_*M1_);
    for (int i = t; i < (M1_*M2_)/4; i += 256) w1dst[i] = ((const float4*)w1g)[i];
  }
  if (t < M1_) { b0s[t] = b0g[t]; b1s[t] = b1g[t]; }
  if (t < M3_) { b2s[t] = b2g[t]; }

  // gather h0 (c-major): rows 0..2 = relative xyz, rows 3..66 = features
  {
    const int k = t >> 3, fg = t & 7;
    int nk = myk_idx;
    if (myk_d > 0.04f) nk = k0_idx;        // ball-query radius clamp
    nk &= (N1_ - 1);
    const float* frow = feat + ((size_t)(b * N1_ + nk)) * F1_ + fg * 8;
    const float4 f0 = *(const float4*)frow;
    const float4 f1 = *(const float4*)(frow + 4);
    const int fb = 3 + fg * 8;
    buf0[(fb+0)*HSTR + k] = f0.x;
    buf0[(fb+1)*HSTR + k] = f0.y;
    buf0[(fb+2)*HSTR + k] = f0.z;
    buf0[(fb+3)*HSTR + k] = f0.w;
    buf0[(fb+4)*HSTR + k] = f1.x;
    buf0[(fb+5)*HSTR + k] = f1.y;
    buf0[(fb+6)*HSTR + k] = f1.z;
    buf0[(fb+7)*HSTR + k] = f1.w;
    if (fg < 3) {
      const float pc = gxyz[(size_t)nk * 3 + fg];
      const float qc = (fg == 0) ? qx : (fg == 1) ? qy : qz;
      buf0[fg * HSTR + k] = __fsub_rn(pc, qc);
    }
  }
  __syncthreads();

#define LEAKY_STORE(acc, mi_, bias, hout) { \
    const float bb = bias[mg*4 + (mi_)]; \
    float4 v; \
    v.x = acc.x + bb; v.x = fmaxf(v.x, 0.2f*v.x); \
    v.y = acc.y + bb; v.y = fmaxf(v.y, 0.2f*v.y); \
    v.z = acc.z + bb; v.z = fmaxf(v.z, 0.2f*v.z); \
    v.w = acc.w + bb; v.w = fmaxf(v.w, 0.2f*v.w); \
    *(float4*)&hout[(mg*4 + (mi_)) * HSTR + kq * 4] = v; }

  // layer 1: 67 -> 64 (threads 0..127, 4m x 4k register tile)
  if (t < 128) {
    const int kq = t & 7, mg = t >> 3;
    float4 a0 = {0,0,0,0}, a1 = {0,0,0,0}, a2 = {0,0,0,0}, a3 = {0,0,0,0};
    const float* w0s = wreg;
    for (int c = 0; c < CIN_; ++c) {
      const float4 wp = *(const float4*)&w0s[c * M1_ + mg * 4];
      const float4 h  = *(const float4*)&buf0[c * HSTR + kq * 4];
      a0.x += h.x*wp.x; a0.y += h.y*wp.x; a0.z += h.z*wp.x; a0.w += h.w*wp.x;
      a1.x += h.x*wp.y; a1.y += h.y*wp.y; a1.z += h.z*wp.y; a1.w += h.w*wp.y;
      a2.x += h.x*wp.z; a2.y += h.y*wp.z; a2.z += h.z*wp.z; a2.w += h.w*wp.z;
      a3.x += h.x*wp.w; a3.y += h.y*wp.w; a3.z += h.z*wp.w; a3.w += h.w*wp.w;
    }
    LEAKY_STORE(a0, 0, b0s, buf1) LEAKY_STORE(a1, 1, b0s, buf1)
    LEAKY_STORE(a2, 2, b0s, buf1) LEAKY_STORE(a3, 3, b0s, buf1)
  }
  __syncthreads();

  // layer 2: 64 -> 64
  if (t < 128) {
    const int kq = t & 7, mg = t >> 3;
    float4 a0 = {0,0,0,0}, a1 = {0,0,0,0}, a2 = {0,0,0,0}, a3 = {0,0,0,0};
    const float* w1s = wreg + CIN_*M1_;
    for (int c = 0; c < M1_; ++c) {
      const float4 wp = *(const float4*)&w1s[c * M2_ + mg * 4];
      const float4 h  = *(const float4*)&buf1[c * HSTR + kq * 4];
      a0.x += h.x*wp.x; a0.y += h.y*wp.x; a0.z += h.z*wp.x; a0.w += h.w*wp.x;
      a1.x += h.x*wp.y; a1.y += h.y*wp.y; a1.z += h.z*wp.y; a1.w += h.w*wp.y;
      a2.x += h.x*wp.z; a2.y += h.y*wp.z; a2.z += h.z*wp.z; a2.w += h.w*wp.z;
      a3.x += h.x*wp.w; a3.y += h.y*wp.w; a3.z += h.z*wp.w; a3.w += h.w*wp.w;
    }
    LEAKY_STORE(a0, 0, b1s, buf0) LEAKY_STORE(a1, 1, b1s, buf0)
    LEAKY_STORE(a2, 2, b1s, buf0) LEAKY_STORE(a3, 3, b1s, buf0)
  }
#undef LEAKY_STORE
  __syncthreads();

  // stage W2 (32 KB) over W0/W1
  for (int i = t; i < (M2_*M3_)/4; i += 256) ((float4*)wreg)[i] = ((const float4*)w2g)[i];
  __syncthreads();

  // layer 3: 64 -> 128, + maxpool over k
  {
    const int kq = t & 7, mg = t >> 3;   // mg in 0..31
    float4 a0 = {0,0,0,0}, a1 = {0,0,0,0}, a2 = {0,0,0,0}, a3 = {0,0,0,0};
    for (int c = 0; c < M2_; ++c) {
      const float4 wp = *(const float4*)&wreg[c * M3_ + mg * 4];
      const float4 h  = *(const float4*)&buf0[c * HSTR + kq * 4];
      a0.x += h.x*wp.x; a0.y += h.y*wp.x; a0.z += h.z*wp.x; a0.w += h.w*wp.x;
      a1.x += h.x*wp.y; a1.y += h.y*wp.y; a1.z += h.z*wp.y; a1.w += h.w*wp.y;
      a2.x += h.x*wp.z; a2.y += h.y*wp.z; a2.z += h.z*wp.z; a2.w += h.w*wp.z;
      a3.x += h.x*wp.w; a3.y += h.y*wp.w; a3.z += h.z*wp.w; a3.w += h.w*wp.w;
    }
    float vm[4];
#define BIAS_LEAKY_HMAX(acc, mi_) { \
      const float bb = b2s[mg*4 + (mi_)]; \
      float vx = acc.x + bb; vx = fmaxf(vx, 0.2f*vx); \
      float vy = acc.y + bb; vy = fmaxf(vy, 0.2f*vy); \
      float vz = acc.z + bb; vz = fmaxf(vz, 0.2f*vz); \
      float vw = acc.w + bb; vw = fmaxf(vw, 0.2f*vw); \
      vm[mi_] = fmaxf(fmaxf(vx, vy), fmaxf(vz, vw)); }
    BIAS_LEAKY_HMAX(a0, 0) BIAS_LEAKY_HMAX(a1, 1) BIAS_LEAKY_HMAX(a2, 2) BIAS_LEAKY_HMAX(a3, 3)
#undef BIAS_LEAKY_HMAX
#pragma unroll
    for (int m = 1; m <= 4; m <<= 1) {
      vm[0] = fmaxf(vm[0], __shfl_xor(vm[0], m, 64));
      vm[1] = fmaxf(vm[1], __shfl_xor(vm[1], m, 64));
      vm[2] = fmaxf(vm[2], __shfl_xor(vm[2], m, 64));
      vm[3] = fmaxf(vm[3], __shfl_xor(vm[3], m, 64));
    }
    if (kq == 0) {
      float4 o; o.x = vm[0]; o.y = vm[1]; o.z = vm[2]; o.w = vm[3];
      *(float4*)&out_feat[(size_t)bq * M3_ + mg * 4] = o;
    }
  }
}

extern "C" void kernel_launch(void* const* d_in, const int* in_sizes, int n_in,
                              void* d_out, int out_size, void* d_ws, size_t ws_size,
                              hipStream_t stream) {
  const float* xyz  = (const float*)d_in[0];
  const float* feat = (const float*)d_in[1];
  const float* w0   = (const float*)d_in[2];
  const float* b0   = (const float*)d_in[3];
  const float* w1   = (const float*)d_in[4];
  const float* b1   = (const float*)d_in[5];
  const float* w2   = (const float*)d_in[6];
  const float* b2   = (const float*)d_in[7];

  float* out_xyz  = (float*)d_out;                  // (8,1024,3) f32
  float* out_feat = out_xyz + B_ * N2_ * 3;         // (8,1024,128) f32

  fps_kernel<<<B_, FTPB, 0, stream>>>(xyz, out_xyz);
  knn_mlp_kernel<<<B_ * N2_, 256, 0, stream>>>(xyz, feat, w0, b0, w1, b1, w2, b2,
                                               out_xyz, out_feat);
}

// Round 7
// 1957.668 us; speedup vs baseline: 2.0486x; 1.2526x over previous
//
#include <hip/hip_runtime.h>

#define B_   8
#define N1_  8192
#define N2_  1024
#define K_   32
#define F1_  64
#define CIN_ 67
#define M1_  64
#define M2_  64
#define M3_  128
#define HSTR 40          // LDS activation row stride (floats)
#define SSTR 36          // KNN d2 per-thread chunk stride (floats)
#define FLTMAX 3.402823466e+38f

#define FTPB 512         // FPS threads per block
#define FNW  (FTPB/64)   // FPS waves per block = 8
#define PPT  (N1_/FTPB)  // points per thread = 16

// order-preserving float->uint key (monotone incl. negatives; equal keys <=> equal bits)
__device__ __forceinline__ unsigned f2key(float f) {
  unsigned u = __float_as_uint(f);
  return u ^ ((unsigned)((int)u >> 31) | 0x80000000u);
}

// 6-step DPP wave64 reduce (row_shr 1/2/4/8 + row_bcast 15/31), result broadcast via readlane(63).
__device__ __forceinline__ unsigned dpp_umax_bcast(unsigned v) {
  unsigned o;
  o = (unsigned)__builtin_amdgcn_update_dpp(0, (int)v, 0x111, 0xf, 0xf, false); v = v > o ? v : o;
  o = (unsigned)__builtin_amdgcn_update_dpp(0, (int)v, 0x112, 0xf, 0xf, false); v = v > o ? v : o;
  o = (unsigned)__builtin_amdgcn_update_dpp(0, (int)v, 0x114, 0xf, 0xf, false); v = v > o ? v : o;
  o = (unsigned)__builtin_amdgcn_update_dpp(0, (int)v, 0x118, 0xf, 0xf, false); v = v > o ? v : o;
  o = (unsigned)__builtin_amdgcn_update_dpp(0, (int)v, 0x142, 0xf, 0xf, false); v = v > o ? v : o;
  o = (unsigned)__builtin_amdgcn_update_dpp(0, (int)v, 0x143, 0xf, 0xf, false); v = v > o ? v : o;
  return (unsigned)__builtin_amdgcn_readlane((int)v, 63);
}
__device__ __forceinline__ unsigned dpp_umin_bcast(unsigned v) {
  unsigned o;
  o = (unsigned)__builtin_amdgcn_update_dpp(-1, (int)v, 0x111, 0xf, 0xf, false); v = v < o ? v : o;
  o = (unsigned)__builtin_amdgcn_update_dpp(-1, (int)v, 0x112, 0xf, 0xf, false); v = v < o ? v : o;
  o = (unsigned)__builtin_amdgcn_update_dpp(-1, (int)v, 0x114, 0xf, 0xf, false); v = v < o ? v : o;
  o = (unsigned)__builtin_amdgcn_update_dpp(-1, (int)v, 0x118, 0xf, 0xf, false); v = v < o ? v : o;
  o = (unsigned)__builtin_amdgcn_update_dpp(-1, (int)v, 0x142, 0xf, 0xf, false); v = v < o ? v : o;
  o = (unsigned)__builtin_amdgcn_update_dpp(-1, (int)v, 0x143, 0xf, 0xf, false); v = v < o ? v : o;
  return (unsigned)__builtin_amdgcn_readlane((int)v, 63);
}

// ---------------- FPS: one block per batch, 1 barrier/iter, DPP reduce, no index tracking ----------------
__global__ __launch_bounds__(FTPB, 1) void fps_kernel(const float* __restrict__ xyz,
                                                      float* __restrict__ out_xyz)
{
  __shared__ float4 wslot[2][FNW];   // {md, x, y, z} per wave winner

  const int t = threadIdx.x;
  const int b = blockIdx.x;
  const float* gxyz = xyz + (size_t)b * (N1_ * 3);
  float* oxyz = out_xyz + (size_t)b * (N2_ * 3);

  float x[PPT], y[PPT], z[PPT], md[PPT];
  {
    const float4* gs = (const float4*)gxyz;
#pragma unroll
    for (int w = 0; w < 12; ++w) {
      const float4 v = gs[t * 12 + w];
#pragma unroll
      for (int c = 0; c < 4; ++c) {
        const int p = w * 4 + c;               // flat float index 0..47
        const float val = (c == 0) ? v.x : (c == 1) ? v.y : (c == 2) ? v.z : v.w;
        const int j = p / 3, cc = p % 3;
        if (cc == 0) x[j] = val; else if (cc == 1) y[j] = val; else z[j] = val;
      }
    }
  }
#pragma unroll
  for (int j = 0; j < PPT; ++j) md[j] = FLTMAX;  // matches jnp.finfo(float32).max init

  const int lane = t & 63, wv_ = t >> 6;
  if (lane == 0) {
    float4 s; s.x = -1.0f; s.y = 0.f; s.z = 0.f; s.w = 0.f;
    wslot[1][wv_] = s;
  }
  if (t == 0) { float4 s; s.x = 1.0f; s.y = x[0]; s.z = y[0]; s.w = z[0]; wslot[1][0] = s; }
  __syncthreads();

  const int n0 = t * PPT;
  for (int i = 1; i < N2_; ++i) {
    const int p = i & 1;
    // winner of iteration i-1: scan 8 slots (strict > keeps lowest wave = lowest idx)
    float4 wb = wslot[p][0];
#pragma unroll
    for (int u = 1; u < FNW; ++u) { const float4 s = wslot[p][u]; if (s.x > wb.x) wb = s; }
    const float px = wb.y, py = wb.z, pz = wb.w;
    if (t == 0) { const int o = (i - 1) * 3; oxyz[o] = px; oxyz[o+1] = py; oxyz[o+2] = pz; }

    // fused distance update + first-max argmax with inline coord tracking
    float bestv, bx, by, bz;
#pragma unroll
    for (int j = 0; j < PPT; ++j) {
      const float dx = __fsub_rn(x[j], px);
      const float dy = __fsub_rn(y[j], py);
      const float dz = __fsub_rn(z[j], pz);
      const float d  = __fadd_rn(__fadd_rn(__fmul_rn(dx,dx), __fmul_rn(dy,dy)), __fmul_rn(dz,dz));
      md[j] = fminf(md[j], d);
      if (j == 0) { bestv = md[0]; bx = x[0]; by = y[0]; bz = z[0]; }
      else {
        const bool c = md[j] > bestv;
        bestv = c ? md[j] : bestv;
        bx = c ? x[j] : bx; by = c ? y[j] : by; bz = c ? z[j] : bz;
      }
    }
    // DPP wave max + ballot winner (lowest lane = lowest point index)
    const unsigned key = f2key(bestv);
    const unsigned kmax = dpp_umax_bcast(key);
    const unsigned long long bm = __ballot(key == kmax);
    const int fl = __ffsll(bm) - 1;
    if (lane == fl) {
      float4 s; s.x = bestv; s.y = bx; s.z = by; s.w = bz;
      wslot[1 - p][wv_] = s;
    }
    __syncthreads();
  }
  if (t == 0) {   // winner of iteration N2_-1 sits in parity-0 slots
    float4 wb = wslot[0][0];
#pragma unroll
    for (int u = 1; u < FNW; ++u) { const float4 s = wslot[0][u]; if (s.x > wb.x) wb = s; }
    const int o = (N2_ - 1) * 3; oxyz[o] = wb.y; oxyz[o+1] = wb.z; oxyz[o+2] = wb.w;
  }
}

// ---------------- Fused KNN + MLP + maxpool: one block per query ----------------
// LDS union: phase 1 d2s (36864 B); phase 2 [wreg 33536 | buf0 10720 | buf1 10240] = 54496 B.
#define SMEM_BYTES 54496
#define OFF_B0 33536
#define OFF_B1 (OFF_B0 + CIN_*HSTR*4)

__global__ __launch_bounds__(256) void knn_mlp_kernel(
    const float* __restrict__ xyz, const float* __restrict__ feat,
    const float* __restrict__ w0g, const float* __restrict__ b0g,
    const float* __restrict__ w1g, const float* __restrict__ b1g,
    const float* __restrict__ w2g, const float* __restrict__ b2g,
    const float* __restrict__ sel_xyz, float* __restrict__ out_feat)
{
  __shared__ __align__(16) char smem[SMEM_BYTES];
  __shared__ float b0s[M1_], b1s[M2_], b2s[M3_];
  __shared__ float sval[2][4];
  __shared__ int   sidx[2][4];

  float* d2s  = (float*)smem;                  // thread-private cells: only owner reads/writes
  float* wreg = (float*)smem;                  // phase-2 weight region
  float* buf0 = (float*)(smem + OFF_B0);
  float* buf1 = (float*)(smem + OFF_B1);

  const int t  = threadIdx.x;
  const int bq = blockIdx.x;
  const int b  = bq >> 10;
  const float* gxyz = xyz + (size_t)b * (N1_ * 3);

  const float qx = sel_xyz[bq*3+0], qy = sel_xyz[bq*3+1], qz = sel_xyz[bq*3+2];
  const float q2 = __fadd_rn(__fadd_rn(__fmul_rn(qx,qx), __fmul_rn(qy,qy)), __fmul_rn(qz,qz));

  // d2 = (q2 + p2) - 2*qp (reference op order), store to private LDS cells, track own min inline
  float mv = FLTMAX; int mi = t * 32;
  {
    float px[32], py[32], pz[32];
    const float4* gs = (const float4*)gxyz;
#pragma unroll
    for (int w = 0; w < 24; ++w) {
      const float4 v = gs[t * 24 + w];
#pragma unroll
      for (int c = 0; c < 4; ++c) {
        const int p = w * 4 + c;
        const float val = (c == 0) ? v.x : (c == 1) ? v.y : (c == 2) ? v.z : v.w;
        const int j = p / 3, cc = p % 3;
        if (cc == 0) px[j] = val; else if (cc == 1) py[j] = val; else pz[j] = val;
      }
    }
#pragma unroll
    for (int g = 0; g < 8; ++g) {
      float vv[4];
#pragma unroll
      for (int c = 0; c < 4; ++c) {
        const int j = 4*g + c;
        const float p2 = __fadd_rn(__fadd_rn(__fmul_rn(px[j],px[j]), __fmul_rn(py[j],py[j])), __fmul_rn(pz[j],pz[j]));
        const float qp = __fadd_rn(__fadd_rn(__fmul_rn(qx,px[j]), __fmul_rn(qy,py[j])), __fmul_rn(qz,pz[j]));
        vv[c] = __fsub_rn(__fadd_rn(q2, p2), __fmul_rn(2.0f, qp));
        if (vv[c] < mv) { mv = vv[c]; mi = t*32 + j; }   // strict <: first (lowest) index
      }
      float4 dv; dv.x = vv[0]; dv.y = vv[1]; dv.z = vv[2]; dv.w = vv[3];
      *(float4*)&d2s[t * SSTR + 4*g] = dv;
    }
  }

  // top-32: 1 barrier/round; DPP min; only the owner of the removed cell rescans
  int   myk_idx = 0;  float myk_d = 0.0f;  int k0_idx = 0;
  const int lane = t & 63;
  for (int kk = 0; kk < K_; ++kk) {
    const int p = kk & 1;
    const unsigned key = f2key(mv);
    const unsigned kmin = dpp_umin_bcast(key);
    const unsigned long long bm = __ballot(key == kmin);
    const int fl = __ffsll(bm) - 1;
    if (lane == fl) { sval[p][t >> 6] = mv; sidx[p][t >> 6] = mi; }
    __syncthreads();
    float wv = sval[p][0]; int wi = sidx[p][0];
#pragma unroll
    for (int u = 1; u < 4; ++u) {
      const float v = sval[p][u]; const int ii = sidx[p][u];
      if (v < wv || (v == wv && ii < wi)) { wv = v; wi = ii; }
    }
    wi &= (N1_ - 1);
    if ((t >> 3) == kk) { myk_idx = wi; myk_d = wv; }
    if (kk == 0) k0_idx = wi;
    if (kk < K_ - 1 && t == (wi >> 5)) {
      d2s[t * SSTR + (wi & 31)] = FLTMAX;            // poke own cell
      float nmv = FLTMAX; int nmi = t * 32;          // rescan own 32 cells
#pragma unroll
      for (int g = 0; g < 8; ++g) {
        const float4 v = *(const float4*)&d2s[t * SSTR + 4*g];
        const int nb = t*32 + 4*g;
        if (v.x < nmv) { nmv = v.x; nmi = nb;   }
        if (v.y < nmv) { nmv = v.y; nmi = nb+1; }
        if (v.z < nmv) { nmv = v.z; nmi = nb+2; }
        if (v.w < nmv) { nmv = v.w; nmi = nb+3; }
      }
      mv = nmv; mi = nmi;
    }
  }

  // -------- phase 2: stage W0+W1 (overwrites d2s), gather h0, MLP, maxpool --------
  for (int i = t; i < (CIN_*M1_)/4; i += 256) ((float4*)wreg)[i] = ((const float4*)w0g)[i];
  {
    float4* w1dst = (float4*)(wreg + CIN_*M1_);
    for (int i = t; i < (M1_*M2_)/4; i += 256) w1dst[i] = ((const float4*)w1g)[i];
  }
  if (t < M1_) { b0s[t] = b0g[t]; b1s[t] = b1g[t]; }
  if (t < M3_) { b2s[t] = b2g[t]; }

  // gather h0 (c-major): rows 0..2 = relative xyz, rows 3..66 = features
  {
    const int k = t >> 3, fg = t & 7;
    int nk = myk_idx;
    if (myk_d > 0.04f) nk = k0_idx;        // ball-query radius clamp
    nk &= (N1_ - 1);
    const float* frow = feat + ((size_t)(b * N1_ + nk)) * F1_ + fg * 8;
    const float4 f0 = *(const float4*)frow;
    const float4 f1 = *(const float4*)(frow + 4);
    const int fb = 3 + fg * 8;
    buf0[(fb+0)*HSTR + k] = f0.x;
    buf0[(fb+1)*HSTR + k] = f0.y;
    buf0[(fb+2)*HSTR + k] = f0.z;
    buf0[(fb+3)*HSTR + k] = f0.w;
    buf0[(fb+4)*HSTR + k] = f1.x;
    buf0[(fb+5)*HSTR + k] = f1.y;
    buf0[(fb+6)*HSTR + k] = f1.z;
    buf0[(fb+7)*HSTR + k] = f1.w;
    if (fg < 3) {
      const float pc = gxyz[(size_t)nk * 3 + fg];
      const float qc = (fg == 0) ? qx : (fg == 1) ? qy : qz;
      buf0[fg * HSTR + k] = __fsub_rn(pc, qc);
    }
  }
  __syncthreads();

#define LEAKY_STORE2(acc, mi_, bias, hout) { \
    const float bb = bias[mg*2 + (mi_)]; \
    float4 v; \
    v.x = acc.x + bb; v.x = fmaxf(v.x, 0.2f*v.x); \
    v.y = acc.y + bb; v.y = fmaxf(v.y, 0.2f*v.y); \
    v.z = acc.z + bb; v.z = fmaxf(v.z, 0.2f*v.z); \
    v.w = acc.w + bb; v.w = fmaxf(v.w, 0.2f*v.w); \
    *(float4*)&hout[(mg*2 + (mi_)) * HSTR + kq * 4] = v; }

  // layer 1: 67 -> 64 (all 256 threads: 2m x 4k tiles; ascending-c order preserved)
  {
    const int kq = t & 7, mg = t >> 3;   // mg 0..31
    float4 a0 = {0,0,0,0}, a1 = {0,0,0,0};
    for (int c = 0; c < CIN_; ++c) {
      const float2 wp = *(const float2*)&wreg[c * M1_ + mg * 2];
      const float4 h  = *(const float4*)&buf0[c * HSTR + kq * 4];
      a0.x += h.x*wp.x; a0.y += h.y*wp.x; a0.z += h.z*wp.x; a0.w += h.w*wp.x;
      a1.x += h.x*wp.y; a1.y += h.y*wp.y; a1.z += h.z*wp.y; a1.w += h.w*wp.y;
    }
    LEAKY_STORE2(a0, 0, b0s, buf1) LEAKY_STORE2(a1, 1, b0s, buf1)
  }
  __syncthreads();

  // layer 2: 64 -> 64
  {
    const int kq = t & 7, mg = t >> 3;
    float4 a0 = {0,0,0,0}, a1 = {0,0,0,0};
    const float* w1s = wreg + CIN_*M1_;
    for (int c = 0; c < M1_; ++c) {
      const float2 wp = *(const float2*)&w1s[c * M2_ + mg * 2];
      const float4 h  = *(const float4*)&buf1[c * HSTR + kq * 4];
      a0.x += h.x*wp.x; a0.y += h.y*wp.x; a0.z += h.z*wp.x; a0.w += h.w*wp.x;
      a1.x += h.x*wp.y; a1.y += h.y*wp.y; a1.z += h.z*wp.y; a1.w += h.w*wp.y;
    }
    LEAKY_STORE2(a0, 0, b1s, buf0) LEAKY_STORE2(a1, 1, b1s, buf0)
  }
#undef LEAKY_STORE2
  __syncthreads();

  // stage W2 (32 KB) over W0/W1
  for (int i = t; i < (M2_*M3_)/4; i += 256) ((float4*)wreg)[i] = ((const float4*)w2g)[i];
  __syncthreads();

  // layer 3: 64 -> 128, + maxpool over k
  {
    const int kq = t & 7, mg = t >> 3;   // mg in 0..31
    float4 a0 = {0,0,0,0}, a1 = {0,0,0,0}, a2 = {0,0,0,0}, a3 = {0,0,0,0};
    for (int c = 0; c < M2_; ++c) {
      const float4 wp = *(const float4*)&wreg[c * M3_ + mg * 4];
      const float4 h  = *(const float4*)&buf0[c * HSTR + kq * 4];
      a0.x += h.x*wp.x; a0.y += h.y*wp.x; a0.z += h.z*wp.x; a0.w += h.w*wp.x;
      a1.x += h.x*wp.y; a1.y += h.y*wp.y; a1.z += h.z*wp.y; a1.w += h.w*wp.y;
      a2.x += h.x*wp.z; a2.y += h.y*wp.z; a2.z += h.z*wp.z; a2.w += h.w*wp.z;
      a3.x += h.x*wp.w; a3.y += h.y*wp.w; a3.z += h.z*wp.w; a3.w += h.w*wp.w;
    }
    float vm[4];
#define BIAS_LEAKY_HMAX(acc, mi_) { \
      const float bb = b2s[mg*4 + (mi_)]; \
      float vx = acc.x + bb; vx = fmaxf(vx, 0.2f*vx); \
      float vy = acc.y + bb; vy = fmaxf(vy, 0.2f*vy); \
      float vz = acc.z + bb; vz = fmaxf(vz, 0.2f*vz); \
      float vw = acc.w + bb; vw = fmaxf(vw, 0.2f*vw); \
      vm[mi_] = fmaxf(fmaxf(vx, vy), fmaxf(vz, vw)); }
    BIAS_LEAKY_HMAX(a0, 0) BIAS_LEAKY_HMAX(a1, 1) BIAS_LEAKY_HMAX(a2, 2) BIAS_LEAKY_HMAX(a3, 3)
#undef BIAS_LEAKY_HMAX
#pragma unroll
    for (int m = 1; m <= 4; m <<= 1) {
      vm[0] = fmaxf(vm[0], __shfl_xor(vm[0], m, 64));
      vm[1] = fmaxf(vm[1], __shfl_xor(vm[1], m, 64));
      vm[2] = fmaxf(vm[2], __shfl_xor(vm[2], m, 64));
      vm[3] = fmaxf(vm[3], __shfl_xor(vm[3], m, 64));
    }
    if (kq == 0) {
      float4 o; o.x = vm[0]; o.y = vm[1]; o.z = vm[2]; o.w = vm[3];
      *(float4*)&out_feat[(size_t)bq * M3_ + mg * 4] = o;
    }
  }
}

extern "C" void kernel_launch(void* const* d_in, const int* in_sizes, int n_in,
                              void* d_out, int out_size, void* d_ws, size_t ws_size,
                              hipStream_t stream) {
  const float* xyz  = (const float*)d_in[0];
  const float* feat = (const float*)d_in[1];
  const float* w0   = (const float*)d_in[2];
  const float* b0   = (const float*)d_in[3];
  const float* w1   = (const float*)d_in[4];
  const float* b1   = (const float*)d_in[5];
  const float* w2   = (const float*)d_in[6];
  const float* b2   = (const float*)d_in[7];

  float* out_xyz  = (float*)d_out;                  // (8,1024,3) f32
  float* out_feat = out_xyz + B_ * N2_ * 3;         // (8,1024,128) f32

  fps_kernel<<<B_, FTPB, 0, stream>>>(xyz, out_xyz);
  knn_mlp_kernel<<<B_ * N2_, 256, 0, stream>>>(xyz, feat, w0, b0, w1, b1, w2, b2,
                                               out_xyz, out_feat);
}

// Round 10
// 1747.490 us; speedup vs baseline: 2.2950x; 1.1203x over previous
//
#include <hip/hip_runtime.h>

#define B_   8
#define N1_  8192
#define N2_  1024
#define K_   32
#define F1_  64
#define CIN_ 67
#define M1_  64
#define M2_  64
#define M3_  128
#define HSTR 40          // LDS activation row stride (floats)
#define FLTMAX 3.402823466e+38f

#define FTPB 512         // FPS threads per block (1024 fails to launch on this harness — R8/R9)
#define FNW  (FTPB/64)   // FPS waves per block = 8
#define PPT  (N1_/FTPB)  // points per thread = 16

// order-preserving float->uint key (monotone incl. negatives; equal keys <=> equal bits)
__device__ __forceinline__ unsigned f2key(float f) {
  unsigned u = __float_as_uint(f);
  return u ^ ((unsigned)((int)u >> 31) | 0x80000000u);
}

// 6-step DPP wave64 reduce (row_shr 1/2/4/8 + row_bcast 15/31), broadcast via readlane(63).
__device__ __forceinline__ unsigned dpp_umax_bcast(unsigned v) {
  unsigned o;
  o = (unsigned)__builtin_amdgcn_update_dpp(0, (int)v, 0x111, 0xf, 0xf, false); v = v > o ? v : o;
  o = (unsigned)__builtin_amdgcn_update_dpp(0, (int)v, 0x112, 0xf, 0xf, false); v = v > o ? v : o;
  o = (unsigned)__builtin_amdgcn_update_dpp(0, (int)v, 0x114, 0xf, 0xf, false); v = v > o ? v : o;
  o = (unsigned)__builtin_amdgcn_update_dpp(0, (int)v, 0x118, 0xf, 0xf, false); v = v > o ? v : o;
  o = (unsigned)__builtin_amdgcn_update_dpp(0, (int)v, 0x142, 0xf, 0xf, false); v = v > o ? v : o;
  o = (unsigned)__builtin_amdgcn_update_dpp(0, (int)v, 0x143, 0xf, 0xf, false); v = v > o ? v : o;
  return (unsigned)__builtin_amdgcn_readlane((int)v, 63);
}
__device__ __forceinline__ unsigned dpp_umin_bcast(unsigned v) {
  unsigned o;
  o = (unsigned)__builtin_amdgcn_update_dpp(-1, (int)v, 0x111, 0xf, 0xf, false); v = v < o ? v : o;
  o = (unsigned)__builtin_amdgcn_update_dpp(-1, (int)v, 0x112, 0xf, 0xf, false); v = v < o ? v : o;
  o = (unsigned)__builtin_amdgcn_update_dpp(-1, (int)v, 0x114, 0xf, 0xf, false); v = v < o ? v : o;
  o = (unsigned)__builtin_amdgcn_update_dpp(-1, (int)v, 0x118, 0xf, 0xf, false); v = v < o ? v : o;
  o = (unsigned)__builtin_amdgcn_update_dpp(-1, (int)v, 0x142, 0xf, 0xf, false); v = v < o ? v : o;
  o = (unsigned)__builtin_amdgcn_update_dpp(-1, (int)v, 0x143, 0xf, 0xf, false); v = v < o ? v : o;
  return (unsigned)__builtin_amdgcn_readlane((int)v, 63);
}

// ---------------- FPS: one block per batch, 1 barrier/iter, DPP reduce (R7-proven) ----------------
__global__ __launch_bounds__(FTPB, 1) void fps_kernel(const float* __restrict__ xyz,
                                                      float* __restrict__ out_xyz)
{
  __shared__ float4 wslot[2][FNW];   // {md, x, y, z} per wave winner

  const int t = threadIdx.x;
  const int b = blockIdx.x;
  const float* gxyz = xyz + (size_t)b * (N1_ * 3);
  float* oxyz = out_xyz + (size_t)b * (N2_ * 3);

  float x[PPT], y[PPT], z[PPT], md[PPT];
  {
    const float4* gs = (const float4*)gxyz;
#pragma unroll
    for (int w = 0; w < 12; ++w) {
      const float4 v = gs[t * 12 + w];
#pragma unroll
      for (int c = 0; c < 4; ++c) {
        const int p = w * 4 + c;               // flat float index 0..47
        const float val = (c == 0) ? v.x : (c == 1) ? v.y : (c == 2) ? v.z : v.w;
        const int j = p / 3, cc = p % 3;
        if (cc == 0) x[j] = val; else if (cc == 1) y[j] = val; else z[j] = val;
      }
    }
  }
#pragma unroll
  for (int j = 0; j < PPT; ++j) md[j] = FLTMAX;  // matches jnp.finfo(float32).max init

  const int lane = t & 63, wv_ = t >> 6;
  if (lane == 0) { float4 s; s.x = -1.0f; s.y = 0.f; s.z = 0.f; s.w = 0.f; wslot[1][wv_] = s; }
  if (t == 0)   { float4 s; s.x = 1.0f; s.y = x[0]; s.z = y[0]; s.w = z[0]; wslot[1][0] = s; }
  __syncthreads();

  for (int i = 1; i < N2_; ++i) {
    const int p = i & 1;
    // winner of iteration i-1: scan 8 slots (strict > keeps lowest wave = lowest idx)
    float4 wb = wslot[p][0];
#pragma unroll
    for (int u = 1; u < FNW; ++u) { const float4 s = wslot[p][u]; if (s.x > wb.x) wb = s; }
    const float px = wb.y, py = wb.z, pz = wb.w;
    if (t == 0) { const int o = (i - 1) * 3; oxyz[o] = px; oxyz[o+1] = py; oxyz[o+2] = pz; }

    // fused distance update + first-max argmax with inline coord tracking
    float bestv, bx, by, bz;
#pragma unroll
    for (int j = 0; j < PPT; ++j) {
      const float dx = __fsub_rn(x[j], px);
      const float dy = __fsub_rn(y[j], py);
      const float dz = __fsub_rn(z[j], pz);
      const float d  = __fadd_rn(__fadd_rn(__fmul_rn(dx,dx), __fmul_rn(dy,dy)), __fmul_rn(dz,dz));
      md[j] = fminf(md[j], d);
      if (j == 0) { bestv = md[0]; bx = x[0]; by = y[0]; bz = z[0]; }
      else {
        const bool c = md[j] > bestv;
        bestv = c ? md[j] : bestv;
        bx = c ? x[j] : bx; by = c ? y[j] : by; bz = c ? z[j] : bz;
      }
    }
    // DPP wave max + ballot winner (lowest lane = lowest point index)
    const unsigned key = f2key(bestv);
    const unsigned kmax = dpp_umax_bcast(key);
    const int fl = __ffsll(__ballot(key == kmax)) - 1;
    if (lane == fl) {
      float4 s; s.x = bestv; s.y = bx; s.z = by; s.w = bz;
      wslot[1 - p][wv_] = s;
    }
    __syncthreads();
  }
  if (t == 0) {   // winner of iteration N2_-1 sits in parity-0 slots
    float4 wb = wslot[0][0];
#pragma unroll
    for (int u = 1; u < FNW; ++u) { const float4 s = wslot[0][u]; if (s.x > wb.x) wb = s; }
    const int o = (N2_ - 1) * 3; oxyz[o] = wb.y; oxyz[o+1] = wb.z; oxyz[o+2] = wb.w;
  }
}

// ---------------- Fused KNN + MLP + maxpool: one block per query ----------------
// d2 lives in registers (top-2 cache + removed bitmask); LDS only buf0/buf1/slots (~21 KB).
__global__ __launch_bounds__(256) void knn_mlp_kernel(
    const float* __restrict__ xyz, const float* __restrict__ feat,
    const float* __restrict__ w0g, const float* __restrict__ b0g,
    const float* __restrict__ w1g, const float* __restrict__ b1g,
    const float* __restrict__ w2g, const float* __restrict__ b2g,
    const float* __restrict__ sel_xyz, float* __restrict__ out_feat)
{
  __shared__ __align__(16) float buf0[CIN_*HSTR];
  __shared__ __align__(16) float buf1[M1_*HSTR];
  __shared__ float sval[2][4];
  __shared__ int   sidx[2][4];

  const int t  = threadIdx.x;
  const int bq = blockIdx.x;
  const int b  = bq >> 10;
  const float* gxyz = xyz + (size_t)b * (N1_ * 3);

  const float qx = sel_xyz[bq*3+0], qy = sel_xyz[bq*3+1], qz = sel_xyz[bq*3+2];
  const float q2 = __fadd_rn(__fadd_rn(__fmul_rn(qx,qx), __fmul_rn(qy,qy)), __fmul_rn(qz,qz));

  // d2 = (q2 + p2) - 2*qp (reference op order) into registers; inline top-2 (lowest-idx ties)
  float d2v[32];
  float m1 = FLTMAX, m2 = FLTMAX; int i1 = t*32, i2 = t*32;
  {
    const float4* gs = (const float4*)gxyz;
#pragma unroll
    for (int g8 = 0; g8 < 4; ++g8) {
      float f[24];
#pragma unroll
      for (int w = 0; w < 6; ++w) {
        const float4 v = gs[t * 24 + g8 * 6 + w];
        f[w*4+0] = v.x; f[w*4+1] = v.y; f[w*4+2] = v.z; f[w*4+3] = v.w;
      }
#pragma unroll
      for (int m = 0; m < 8; ++m) {
        const int j = g8 * 8 + m;
        const float px = f[3*m], py = f[3*m+1], pz = f[3*m+2];
        const float p2 = __fadd_rn(__fadd_rn(__fmul_rn(px,px), __fmul_rn(py,py)), __fmul_rn(pz,pz));
        const float qp = __fadd_rn(__fadd_rn(__fmul_rn(qx,px), __fmul_rn(qy,py)), __fmul_rn(qz,pz));
        const float d  = __fsub_rn(__fadd_rn(q2, p2), __fmul_rn(2.0f, qp));
        d2v[j] = d;
        const int idx = t*32 + j;
        const bool c1 = d < m1;
        const bool c2 = d < m2;
        const float nm2 = c1 ? m1 : (c2 ? d : m2);
        const int   ni2 = c1 ? i1 : (c2 ? idx : i2);
        m1 = c1 ? d : m1; i1 = c1 ? idx : i1;
        m2 = nm2; i2 = ni2;
      }
    }
  }

  // top-32: 1 barrier/round; DPP min; extraction promotes cached 2nd-min, rescan only if stale
  int myk_idx = 0; float myk_d = 0.0f; int k0_idx = 0;
  unsigned removed = 0u; bool have2 = true;
  const int lane = t & 63;
  for (int kk = 0; kk < K_; ++kk) {
    const int p = kk & 1;
    const unsigned key = f2key(m1);
    const unsigned kmin = dpp_umin_bcast(key);
    const int fl = __ffsll(__ballot(key == kmin)) - 1;
    if (lane == fl) { sval[p][t >> 6] = m1; sidx[p][t >> 6] = i1; }
    __syncthreads();
    float wv = sval[p][0]; int wi = sidx[p][0];
#pragma unroll
    for (int u = 1; u < 4; ++u) {
      const float v = sval[p][u]; const int ii = sidx[p][u];
      if (v < wv || (v == wv && ii < wi)) { wv = v; wi = ii; }
    }
    wi &= (N1_ - 1);
    if ((t >> 3) == kk) { myk_idx = wi; myk_d = wv; }
    if (kk == 0) k0_idx = wi;
    if (kk < K_ - 1 && t == (wi >> 5)) {
      removed |= 1u << (wi & 31);
      if (have2) { m1 = m2; i1 = i2; have2 = false; }
      else {
        m1 = FLTMAX; i1 = t*32; m2 = FLTMAX; i2 = t*32;
#pragma unroll
        for (int j = 0; j < 32; ++j) {
          const float d = ((removed >> j) & 1u) ? FLTMAX : d2v[j];
          const int idx = t*32 + j;
          const bool c1 = d < m1;
          const bool c2 = d < m2;
          const float nm2 = c1 ? m1 : (c2 ? d : m2);
          const int   ni2 = c1 ? i1 : (c2 ? idx : i2);
          m1 = c1 ? d : m1; i1 = c1 ? idx : i1;
          m2 = nm2; i2 = ni2;
        }
        have2 = true;
      }
    }
  }

  // -------- phase 2: gather h0, MLP (weights direct from global/L1), maxpool --------
  {
    const int k = t >> 3, fg = t & 7;
    int nk = myk_idx;
    if (myk_d > 0.04f) nk = k0_idx;        // ball-query radius clamp
    nk &= (N1_ - 1);
    const float* frow = feat + ((size_t)(b * N1_ + nk)) * F1_ + fg * 8;
    const float4 f0 = *(const float4*)frow;
    const float4 f1 = *(const float4*)(frow + 4);
    const int fb = 3 + fg * 8;
    buf0[(fb+0)*HSTR + k] = f0.x;
    buf0[(fb+1)*HSTR + k] = f0.y;
    buf0[(fb+2)*HSTR + k] = f0.z;
    buf0[(fb+3)*HSTR + k] = f0.w;
    buf0[(fb+4)*HSTR + k] = f1.x;
    buf0[(fb+5)*HSTR + k] = f1.y;
    buf0[(fb+6)*HSTR + k] = f1.z;
    buf0[(fb+7)*HSTR + k] = f1.w;
    if (fg < 3) {
      const float pc = gxyz[(size_t)nk * 3 + fg];
      const float qc = (fg == 0) ? qx : (fg == 1) ? qy : qz;
      buf0[fg * HSTR + k] = __fsub_rn(pc, qc);
    }
  }
  __syncthreads();

#define LEAKY_STORE2(acc, mi_, biasg, hout) { \
    const float bb = biasg[mg*2 + (mi_)]; \
    float4 v; \
    v.x = acc.x + bb; v.x = fmaxf(v.x, 0.2f*v.x); \
    v.y = acc.y + bb; v.y = fmaxf(v.y, 0.2f*v.y); \
    v.z = acc.z + bb; v.z = fmaxf(v.z, 0.2f*v.z); \
    v.w = acc.w + bb; v.w = fmaxf(v.w, 0.2f*v.w); \
    *(float4*)&hout[(mg*2 + (mi_)) * HSTR + kq * 4] = v; }

  // layer 1: 67 -> 64 (all 256 threads: 2m x 4k tiles; ascending-c order)
  {
    const int kq = t & 7, mg = t >> 3;   // mg 0..31
    float4 a0 = {0,0,0,0}, a1 = {0,0,0,0};
#pragma unroll 4
    for (int c = 0; c < CIN_; ++c) {
      const float2 wp = *(const float2*)&w0g[c * M1_ + mg * 2];
      const float4 h  = *(const float4*)&buf0[c * HSTR + kq * 4];
      a0.x += h.x*wp.x; a0.y += h.y*wp.x; a0.z += h.z*wp.x; a0.w += h.w*wp.x;
      a1.x += h.x*wp.y; a1.y += h.y*wp.y; a1.z += h.z*wp.y; a1.w += h.w*wp.y;
    }
    LEAKY_STORE2(a0, 0, b0g, buf1) LEAKY_STORE2(a1, 1, b0g, buf1)
  }
  __syncthreads();

  // layer 2: 64 -> 64
  {
    const int kq = t & 7, mg = t >> 3;
    float4 a0 = {0,0,0,0}, a1 = {0,0,0,0};
#pragma unroll 4
    for (int c = 0; c < M1_; ++c) {
      const float2 wp = *(const float2*)&w1g[c * M2_ + mg * 2];
      const float4 h  = *(const float4*)&buf1[c * HSTR + kq * 4];
      a0.x += h.x*wp.x; a0.y += h.y*wp.x; a0.z += h.z*wp.x; a0.w += h.w*wp.x;
      a1.x += h.x*wp.y; a1.y += h.y*wp.y; a1.z += h.z*wp.y; a1.w += h.w*wp.y;
    }
    LEAKY_STORE2(a0, 0, b1g, buf0) LEAKY_STORE2(a1, 1, b1g, buf0)
  }
#undef LEAKY_STORE2
  __syncthreads();

  // layer 3: 64 -> 128, + maxpool over k
  {
    const int kq = t & 7, mg = t >> 3;   // mg in 0..31
    float4 a0 = {0,0,0,0}, a1 = {0,0,0,0}, a2 = {0,0,0,0}, a3 = {0,0,0,0};
#pragma unroll 4
    for (int c = 0; c < M2_; ++c) {
      const float4 wp = *(const float4*)&w2g[c * M3_ + mg * 4];
      const float4 h  = *(const float4*)&buf0[c * HSTR + kq * 4];
      a0.x += h.x*wp.x; a0.y += h.y*wp.x; a0.z += h.z*wp.x; a0.w += h.w*wp.x;
      a1.x += h.x*wp.y; a1.y += h.y*wp.y; a1.z += h.z*wp.y; a1.w += h.w*wp.y;
      a2.x += h.x*wp.z; a2.y += h.y*wp.z; a2.z += h.z*wp.z; a2.w += h.w*wp.z;
      a3.x += h.x*wp.w; a3.y += h.y*wp.w; a3.z += h.z*wp.w; a3.w += h.w*wp.w;
    }
    float vm[4];
#define BIAS_LEAKY_HMAX(acc, mi_) { \
      const float bb = b2g[mg*4 + (mi_)]; \
      float vx = acc.x + bb; vx = fmaxf(vx, 0.2f*vx); \
      float vy = acc.y + bb; vy = fmaxf(vy, 0.2f*vy); \
      float vz = acc.z + bb; vz = fmaxf(vz, 0.2f*vz); \
      float vw = acc.w + bb; vw = fmaxf(vw, 0.2f*vw); \
      vm[mi_] = fmaxf(fmaxf(vx, vy), fmaxf(vz, vw)); }
    BIAS_LEAKY_HMAX(a0, 0) BIAS_LEAKY_HMAX(a1, 1) BIAS_LEAKY_HMAX(a2, 2) BIAS_LEAKY_HMAX(a3, 3)
#undef BIAS_LEAKY_HMAX
#pragma unroll
    for (int m = 1; m <= 4; m <<= 1) {
      vm[0] = fmaxf(vm[0], __shfl_xor(vm[0], m, 64));
      vm[1] = fmaxf(vm[1], __shfl_xor(vm[1], m, 64));
      vm[2] = fmaxf(vm[2], __shfl_xor(vm[2], m, 64));
      vm[3] = fmaxf(vm[3], __shfl_xor(vm[3], m, 64));
    }
    if (kq == 0) {
      float4 o; o.x = vm[0]; o.y = vm[1]; o.z = vm[2]; o.w = vm[3];
      *(float4*)&out_feat[(size_t)bq * M3_ + mg * 4] = o;
    }
  }
}

extern "C" void kernel_launch(void* const* d_in, const int* in_sizes, int n_in,
                              void* d_out, int out_size, void* d_ws, size_t ws_size,
                              hipStream_t stream) {
  const float* xyz  = (const float*)d_in[0];
  const float* feat = (const float*)d_in[1];
  const float* w0   = (const float*)d_in[2];
  const float* b0   = (const float*)d_in[3];
  const float* w1   = (const float*)d_in[4];
  const float* b1   = (const float*)d_in[5];
  const float* w2   = (const float*)d_in[6];
  const float* b2   = (const float*)d_in[7];

  float* out_xyz  = (float*)d_out;                  // (8,1024,3) f32
  float* out_feat = out_xyz + B_ * N2_ * 3;         // (8,1024,128) f32

  fps_kernel<<<B_, FTPB, 0, stream>>>(xyz, out_xyz);
  knn_mlp_kernel<<<B_ * N2_, 256, 0, stream>>>(xyz, feat, w0, b0, w1, b1, w2, b2,
                                               out_xyz, out_feat);
}

// Round 11
// 1474.202 us; speedup vs baseline: 2.7205x; 1.1854x over previous
//
#include <hip/hip_runtime.h>

#define B_   8
#define N1_  8192
#define N2_  1024
#define K_   32
#define F1_  64
#define CIN_ 67
#define M1_  64
#define M2_  64
#define M3_  128
#define HSTR 40          // LDS activation row stride (floats)
#define FLTMAX 3.402823466e+38f

#define FNW  4           // FPS waves per block (256 threads)
#define PPT  32          // FPS points per thread

// order-preserving float->uint key (monotone incl. negatives; equal keys <=> equal bits)
__device__ __forceinline__ unsigned f2key(float f) {
  unsigned u = __float_as_uint(f);
  return u ^ ((unsigned)((int)u >> 31) | 0x80000000u);
}

// 6-step DPP wave64 reduce (row_shr 1/2/4/8 + row_bcast 15/31), broadcast via readlane(63).
__device__ __forceinline__ unsigned dpp_umax_bcast(unsigned v) {
  unsigned o;
  o = (unsigned)__builtin_amdgcn_update_dpp(0, (int)v, 0x111, 0xf, 0xf, false); v = v > o ? v : o;
  o = (unsigned)__builtin_amdgcn_update_dpp(0, (int)v, 0x112, 0xf, 0xf, false); v = v > o ? v : o;
  o = (unsigned)__builtin_amdgcn_update_dpp(0, (int)v, 0x114, 0xf, 0xf, false); v = v > o ? v : o;
  o = (unsigned)__builtin_amdgcn_update_dpp(0, (int)v, 0x118, 0xf, 0xf, false); v = v > o ? v : o;
  o = (unsigned)__builtin_amdgcn_update_dpp(0, (int)v, 0x142, 0xf, 0xf, false); v = v > o ? v : o;
  o = (unsigned)__builtin_amdgcn_update_dpp(0, (int)v, 0x143, 0xf, 0xf, false); v = v > o ? v : o;
  return (unsigned)__builtin_amdgcn_readlane((int)v, 63);
}
__device__ __forceinline__ unsigned dpp_umin_bcast(unsigned v) {
  unsigned o;
  o = (unsigned)__builtin_amdgcn_update_dpp(-1, (int)v, 0x111, 0xf, 0xf, false); v = v < o ? v : o;
  o = (unsigned)__builtin_amdgcn_update_dpp(-1, (int)v, 0x112, 0xf, 0xf, false); v = v < o ? v : o;
  o = (unsigned)__builtin_amdgcn_update_dpp(-1, (int)v, 0x114, 0xf, 0xf, false); v = v < o ? v : o;
  o = (unsigned)__builtin_amdgcn_update_dpp(-1, (int)v, 0x118, 0xf, 0xf, false); v = v < o ? v : o;
  o = (unsigned)__builtin_amdgcn_update_dpp(-1, (int)v, 0x142, 0xf, 0xf, false); v = v < o ? v : o;
  o = (unsigned)__builtin_amdgcn_update_dpp(-1, (int)v, 0x143, 0xf, 0xf, false); v = v < o ? v : o;
  return (unsigned)__builtin_amdgcn_readlane((int)v, 63);
}

// handshake encode: coords in [0,1) -> bits in [0xC0000000, 0xFF7FFFFF]; never 0x0 (memset) or 0xAAAAAAAA (poison)
#define HS_ENC(f) (__float_as_uint(f) ^ 0xC0000000u)
#define HS_DEC(u) __uint_as_float((u) ^ 0xC0000000u)

__global__ __launch_bounds__(256, 1) void fused_kernel(
    const float* __restrict__ xyz, const float* __restrict__ feat,
    const float* __restrict__ w0g, const float* __restrict__ b0g,
    const float* __restrict__ w1g, const float* __restrict__ b1g,
    const float* __restrict__ w2g, const float* __restrict__ b2g,
    float* __restrict__ out_xyz, float* __restrict__ out_feat)
{
  __shared__ float4 wslot[2][FNW];                  // fps winner slots
  __shared__ __align__(16) float buf0[CIN_*HSTR];   // knn activations
  __shared__ __align__(16) float buf1[M1_*HSTR];
  __shared__ float sval[2][4];
  __shared__ int   sidx[2][4];
  __shared__ float qsh[3];

  const int t = threadIdx.x;
  const int lane = t & 63;

  if (blockIdx.x < B_) {
    // ================= FPS producer: one block per batch =================
    __builtin_amdgcn_s_setprio(3);   // protect the sequential critical path from co-resident knn waves
    const int b = blockIdx.x;
    const float* gxyz = xyz + (size_t)b * (N1_ * 3);
    float* oxyz = out_xyz + (size_t)b * (N2_ * 3);

    float x[PPT], y[PPT], z[PPT], md[PPT];
    {
      const float4* gs = (const float4*)gxyz;
#pragma unroll
      for (int w = 0; w < 24; ++w) {
        const float4 v = gs[t * 24 + w];
#pragma unroll
        for (int c = 0; c < 4; ++c) {
          const int p = w * 4 + c;               // flat float index 0..95
          const float val = (c == 0) ? v.x : (c == 1) ? v.y : (c == 2) ? v.z : v.w;
          const int j = p / 3, cc = p % 3;
          if (cc == 0) x[j] = val; else if (cc == 1) y[j] = val; else z[j] = val;
        }
      }
    }
#pragma unroll
    for (int j = 0; j < PPT; ++j) md[j] = FLTMAX;  // matches jnp.finfo(float32).max init

    const int wv_ = t >> 6;
    if (lane == 0) { float4 s; s.x = -1.0f; s.y = 0.f; s.z = 0.f; s.w = 0.f; wslot[1][wv_] = s; }
    if (t == 0)   { float4 s; s.x = 1.0f; s.y = x[0]; s.z = y[0]; s.w = z[0]; wslot[1][0] = s; }
    __syncthreads();

    for (int i = 1; i < N2_; ++i) {
      const int p = i & 1;
      // winner of iteration i-1: scan 4 slots (strict > keeps lowest wave = lowest idx)
      float4 wb = wslot[p][0];
#pragma unroll
      for (int u = 1; u < FNW; ++u) { const float4 s = wslot[p][u]; if (s.x > wb.x) wb = s; }
      const float px = wb.y, py = wb.z, pz = wb.w;
      if (t == 0) {
        const int g = (b << 10) + (i - 1);
        const int o = (i - 1) * 3;
        oxyz[o] = px; oxyz[o+1] = py; oxyz[o+2] = pz;
        unsigned* hs = (unsigned*)(out_feat + (size_t)g * M3_);
        atomicExch(&hs[0], HS_ENC(px));
        atomicExch(&hs[1], HS_ENC(py));
        atomicExch(&hs[2], HS_ENC(pz));
      }

      // fused distance update + first-max argmax with inline coord tracking
      float bestv, bx, by, bz;
#pragma unroll
      for (int j = 0; j < PPT; ++j) {
        const float dx = __fsub_rn(x[j], px);
        const float dy = __fsub_rn(y[j], py);
        const float dz = __fsub_rn(z[j], pz);
        const float d  = __fadd_rn(__fadd_rn(__fmul_rn(dx,dx), __fmul_rn(dy,dy)), __fmul_rn(dz,dz));
        md[j] = fminf(md[j], d);
        if (j == 0) { bestv = md[0]; bx = x[0]; by = y[0]; bz = z[0]; }
        else {
          const bool c = md[j] > bestv;
          bestv = c ? md[j] : bestv;
          bx = c ? x[j] : bx; by = c ? y[j] : by; bz = c ? z[j] : bz;
        }
      }
      // DPP wave max + ballot winner (lowest lane = lowest point index)
      const unsigned key = f2key(bestv);
      const unsigned kmax = dpp_umax_bcast(key);
      const int fl = __ffsll(__ballot(key == kmax)) - 1;
      if (lane == fl) {
        float4 s; s.x = bestv; s.y = bx; s.z = by; s.w = bz;
        wslot[1 - p][wv_] = s;
      }
      __syncthreads();
    }
    if (t == 0) {   // winner of iteration N2_-1 sits in parity-0 slots
      float4 wb = wslot[0][0];
#pragma unroll
      for (int u = 1; u < FNW; ++u) { const float4 s = wslot[0][u]; if (s.x > wb.x) wb = s; }
      const int g = (b << 10) + (N2_ - 1);
      const int o = (N2_ - 1) * 3;
      oxyz[o] = wb.y; oxyz[o+1] = wb.z; oxyz[o+2] = wb.w;
      unsigned* hs = (unsigned*)(out_feat + (size_t)g * M3_);
      atomicExch(&hs[0], HS_ENC(wb.y));
      atomicExch(&hs[1], HS_ENC(wb.z));
      atomicExch(&hs[2], HS_ENC(wb.w));
    }
    return;
  }

  // ================= KNN + MLP + maxpool consumer: one block per query =================
  const int bq = blockIdx.x - B_;
  const int b  = bq >> 10;
  const float* gxyz = xyz + (size_t)b * (N1_ * 3);

  if (t == 0) {
    unsigned* hs = (unsigned*)(out_feat + (size_t)bq * M3_);
#pragma unroll
    for (int w = 0; w < 3; ++w) {
      unsigned v;
      do { __builtin_amdgcn_s_sleep(2); v = atomicOr(&hs[w], 0u); }
      while (v == 0u || v == 0xAAAAAAAAu);
      qsh[w] = HS_DEC(v);
    }
  }
  __syncthreads();
  const float qx = qsh[0], qy = qsh[1], qz = qsh[2];
  const float q2 = __fadd_rn(__fadd_rn(__fmul_rn(qx,qx), __fmul_rn(qy,qy)), __fmul_rn(qz,qz));

  // d2 = (q2 + p2) - 2*qp (reference op order) into registers; inline top-2 (lowest-idx ties)
  float d2v[32];
  float m1 = FLTMAX, m2 = FLTMAX; int i1 = t*32, i2 = t*32;
  {
    const float4* gs = (const float4*)gxyz;
#pragma unroll
    for (int g8 = 0; g8 < 4; ++g8) {
      float f[24];
#pragma unroll
      for (int w = 0; w < 6; ++w) {
        const float4 v = gs[t * 24 + g8 * 6 + w];
        f[w*4+0] = v.x; f[w*4+1] = v.y; f[w*4+2] = v.z; f[w*4+3] = v.w;
      }
#pragma unroll
      for (int m = 0; m < 8; ++m) {
        const int j = g8 * 8 + m;
        const float px = f[3*m], py = f[3*m+1], pz = f[3*m+2];
        const float p2 = __fadd_rn(__fadd_rn(__fmul_rn(px,px), __fmul_rn(py,py)), __fmul_rn(pz,pz));
        const float qp = __fadd_rn(__fadd_rn(__fmul_rn(qx,px), __fmul_rn(qy,py)), __fmul_rn(qz,pz));
        const float d  = __fsub_rn(__fadd_rn(q2, p2), __fmul_rn(2.0f, qp));
        d2v[j] = d;
        const int idx = t*32 + j;
        const bool c1 = d < m1;
        const bool c2 = d < m2;
        const float nm2 = c1 ? m1 : (c2 ? d : m2);
        const int   ni2 = c1 ? i1 : (c2 ? idx : i2);
        m1 = c1 ? d : m1; i1 = c1 ? idx : i1;
        m2 = nm2; i2 = ni2;
      }
    }
  }

  // top-32: 1 barrier/round; DPP min; extraction promotes cached 2nd-min, rescan only if stale
  int myk_idx = 0; float myk_d = 0.0f; int k0_idx = 0;
  unsigned removed = 0u; bool have2 = true;
  for (int kk = 0; kk < K_; ++kk) {
    const int p = kk & 1;
    const unsigned key = f2key(m1);
    const unsigned kmin = dpp_umin_bcast(key);
    const int fl = __ffsll(__ballot(key == kmin)) - 1;
    if (lane == fl) { sval[p][t >> 6] = m1; sidx[p][t >> 6] = i1; }
    __syncthreads();
    float wv = sval[p][0]; int wi = sidx[p][0];
#pragma unroll
    for (int u = 1; u < 4; ++u) {
      const float v = sval[p][u]; const int ii = sidx[p][u];
      if (v < wv || (v == wv && ii < wi)) { wv = v; wi = ii; }
    }
    wi &= (N1_ - 1);
    if ((t >> 3) == kk) { myk_idx = wi; myk_d = wv; }
    if (kk == 0) k0_idx = wi;
    if (kk < K_ - 1 && t == (wi >> 5)) {
      removed |= 1u << (wi & 31);
      if (have2) { m1 = m2; i1 = i2; have2 = false; }
      else {
        m1 = FLTMAX; i1 = t*32; m2 = FLTMAX; i2 = t*32;
#pragma unroll
        for (int j = 0; j < 32; ++j) {
          const float d = ((removed >> j) & 1u) ? FLTMAX : d2v[j];
          const int idx = t*32 + j;
          const bool c1 = d < m1;
          const bool c2 = d < m2;
          const float nm2 = c1 ? m1 : (c2 ? d : m2);
          const int   ni2 = c1 ? i1 : (c2 ? idx : i2);
          m1 = c1 ? d : m1; i1 = c1 ? idx : i1;
          m2 = nm2; i2 = ni2;
        }
        have2 = true;
      }
    }
  }

  // -------- phase 2: gather h0, MLP (weights direct from global/L1), maxpool --------
  {
    const int k = t >> 3, fg = t & 7;
    int nk = myk_idx;
    if (myk_d > 0.04f) nk = k0_idx;        // ball-query radius clamp
    nk &= (N1_ - 1);
    const float* frow = feat + ((size_t)(b * N1_ + nk)) * F1_ + fg * 8;
    const float4 f0 = *(const float4*)frow;
    const float4 f1 = *(const float4*)(frow + 4);
    const int fb = 3 + fg * 8;
    buf0[(fb+0)*HSTR + k] = f0.x;
    buf0[(fb+1)*HSTR + k] = f0.y;
    buf0[(fb+2)*HSTR + k] = f0.z;
    buf0[(fb+3)*HSTR + k] = f0.w;
    buf0[(fb+4)*HSTR + k] = f1.x;
    buf0[(fb+5)*HSTR + k] = f1.y;
    buf0[(fb+6)*HSTR + k] = f1.z;
    buf0[(fb+7)*HSTR + k] = f1.w;
    if (fg < 3) {
      const float pc = gxyz[(size_t)nk * 3 + fg];
      const float qc = (fg == 0) ? qx : (fg == 1) ? qy : qz;
      buf0[fg * HSTR + k] = __fsub_rn(pc, qc);
    }
  }
  __syncthreads();

#define LEAKY_STORE2(acc, mi_, biasg, hout) { \
    const float bb = biasg[mg*2 + (mi_)]; \
    float4 v; \
    v.x = acc.x + bb; v.x = fmaxf(v.x, 0.2f*v.x); \
    v.y = acc.y + bb; v.y = fmaxf(v.y, 0.2f*v.y); \
    v.z = acc.z + bb; v.z = fmaxf(v.z, 0.2f*v.z); \
    v.w = acc.w + bb; v.w = fmaxf(v.w, 0.2f*v.w); \
    *(float4*)&hout[(mg*2 + (mi_)) * HSTR + kq * 4] = v; }

  // layer 1: 67 -> 64 (all 256 threads: 2m x 4k tiles; ascending-c order)
  {
    const int kq = t & 7, mg = t >> 3;   // mg 0..31
    float4 a0 = {0,0,0,0}, a1 = {0,0,0,0};
#pragma unroll 4
    for (int c = 0; c < CIN_; ++c) {
      const float2 wp = *(const float2*)&w0g[c * M1_ + mg * 2];
      const float4 h  = *(const float4*)&buf0[c * HSTR + kq * 4];
      a0.x += h.x*wp.x; a0.y += h.y*wp.x; a0.z += h.z*wp.x; a0.w += h.w*wp.x;
      a1.x += h.x*wp.y; a1.y += h.y*wp.y; a1.z += h.z*wp.y; a1.w += h.w*wp.y;
    }
    LEAKY_STORE2(a0, 0, b0g, buf1) LEAKY_STORE2(a1, 1, b0g, buf1)
  }
  __syncthreads();

  // layer 2: 64 -> 64
  {
    const int kq = t & 7, mg = t >> 3;
    float4 a0 = {0,0,0,0}, a1 = {0,0,0,0};
#pragma unroll 4
    for (int c = 0; c < M1_; ++c) {
      const float2 wp = *(const float2*)&w1g[c * M2_ + mg * 2];
      const float4 h  = *(const float4*)&buf1[c * HSTR + kq * 4];
      a0.x += h.x*wp.x; a0.y += h.y*wp.x; a0.z += h.z*wp.x; a0.w += h.w*wp.x;
      a1.x += h.x*wp.y; a1.y += h.y*wp.y; a1.z += h.z*wp.y; a1.w += h.w*wp.y;
    }
    LEAKY_STORE2(a0, 0, b1g, buf0) LEAKY_STORE2(a1, 1, b1g, buf0)
  }
#undef LEAKY_STORE2
  __syncthreads();

  // layer 3: 64 -> 128, + maxpool over k
  {
    const int kq = t & 7, mg = t >> 3;   // mg in 0..31
    float4 a0 = {0,0,0,0}, a1 = {0,0,0,0}, a2 = {0,0,0,0}, a3 = {0,0,0,0};
#pragma unroll 4
    for (int c = 0; c < M2_; ++c) {
      const float4 wp = *(const float4*)&w2g[c * M3_ + mg * 4];
      const float4 h  = *(const float4*)&buf0[c * HSTR + kq * 4];
      a0.x += h.x*wp.x; a0.y += h.y*wp.x; a0.z += h.z*wp.x; a0.w += h.w*wp.x;
      a1.x += h.x*wp.y; a1.y += h.y*wp.y; a1.z += h.z*wp.y; a1.w += h.w*wp.y;
      a2.x += h.x*wp.z; a2.y += h.y*wp.z; a2.z += h.z*wp.z; a2.w += h.w*wp.z;
      a3.x += h.x*wp.w; a3.y += h.y*wp.w; a3.z += h.z*wp.w; a3.w += h.w*wp.w;
    }
    float vm[4];
#define BIAS_LEAKY_HMAX(acc, mi_) { \
      const float bb = b2g[mg*4 + (mi_)]; \
      float vx = acc.x + bb; vx = fmaxf(vx, 0.2f*vx); \
      float vy = acc.y + bb; vy = fmaxf(vy, 0.2f*vy); \
      float vz = acc.z + bb; vz = fmaxf(vz, 0.2f*vz); \
      float vw = acc.w + bb; vw = fmaxf(vw, 0.2f*vw); \
      vm[mi_] = fmaxf(fmaxf(vx, vy), fmaxf(vz, vw)); }
    BIAS_LEAKY_HMAX(a0, 0) BIAS_LEAKY_HMAX(a1, 1) BIAS_LEAKY_HMAX(a2, 2) BIAS_LEAKY_HMAX(a3, 3)
#undef BIAS_LEAKY_HMAX
#pragma unroll
    for (int m = 1; m <= 4; m <<= 1) {
      vm[0] = fmaxf(vm[0], __shfl_xor(vm[0], m, 64));
      vm[1] = fmaxf(vm[1], __shfl_xor(vm[1], m, 64));
      vm[2] = fmaxf(vm[2], __shfl_xor(vm[2], m, 64));
      vm[3] = fmaxf(vm[3], __shfl_xor(vm[3], m, 64));
    }
    if (kq == 0) {
      float4 o; o.x = vm[0]; o.y = vm[1]; o.z = vm[2]; o.w = vm[3];
      *(float4*)&out_feat[(size_t)bq * M3_ + mg * 4] = o;   // overwrites this query's handshake words
    }
  }
}

extern "C" void kernel_launch(void* const* d_in, const int* in_sizes, int n_in,
                              void* d_out, int out_size, void* d_ws, size_t ws_size,
                              hipStream_t stream) {
  const float* xyz  = (const float*)d_in[0];
  const float* feat = (const float*)d_in[1];
  const float* w0   = (const float*)d_in[2];
  const float* b0   = (const float*)d_in[3];
  const float* w1   = (const float*)d_in[4];
  const float* b1   = (const float*)d_in[5];
  const float* w2   = (const float*)d_in[6];
  const float* b2   = (const float*)d_in[7];

  float* out_xyz  = (float*)d_out;                  // (8,1024,3) f32
  float* out_feat = out_xyz + B_ * N2_ * 3;         // (8,1024,128) f32

  fused_kernel<<<B_ + B_ * N2_, 256, 0, stream>>>(xyz, feat, w0, b0, w1, b1, w2, b2,
                                                  out_xyz, out_feat);
}